// Round 7
// baseline (649.819 us; speedup 1.0000x reference)
//
#include <hip/hip_runtime.h>

typedef _Float16 f16x8 __attribute__((ext_vector_type(8)));
typedef float    f32x4 __attribute__((ext_vector_type(4)));

constexpr int BATCH = 2048;
constexpr int SEQ   = 512;
constexpr int H     = 50;
constexpr int NB    = 8;    // batch per block -> 256 blocks = 1 per CU
constexpr int NT    = 512;  // 8 waves, 2 per SIMD
constexpr int MT    = 13;   // M tiles of 16 (208 rows >= 200); wave w: m=w, w+8
constexpr int KQ    = 7;    // panel k-chunks of 32 (K=224)
constexpr int PSZ   = KQ * 64 * 8;   // panel halfs (3584)

__device__ __forceinline__ float fexp2(float x) { return __builtin_amdgcn_exp2f(x); }
__device__ __forceinline__ float frcp(float x)  { return __builtin_amdgcn_rcpf(x); }
__device__ __forceinline__ float sigm(float x) {
    return frcp(1.0f + fexp2(-1.4426950408889634f * x));
}
__device__ __forceinline__ float tanh_fast(float x) {
    float a = fexp2(-2.8853900817779268f * fabsf(x));
    return copysignf((1.0f - a) * frcp(1.0f + a), x);
}
__device__ __forceinline__ _Float16 f16hi(float w) { return (_Float16)w; }
__device__ __forceinline__ _Float16 f16lo(float w) {
    _Float16 h = (_Float16)w; return (_Float16)(w - (float)h);
}
// B-panel frag-linear address (halfs) for value (k, n), k<224, n<16
__device__ __forceinline__ int baddr(int k, int n) {
    return (((k >> 5) * 64) + (((k >> 3) & 3) * 16) + n) * 8 + (k & 7);
}
union H2U { unsigned u; _Float16 h[2]; };

// Panel k-map: 0..49 h1_hi | 50..99 h1_lo | 100,101 x_hi,x_lo |
//              112..161 h2_hi | 162..211 h2_lo | rest 0
// GATE PERMUTATION (as r6): A phys row w (in tile m) <-> j = 4m + (w>>2),
// gate = w&3, logical W row = gate*H + j.  After MFMA, lane (quad,nn) of
// tile m holds acc[r] = gate r of hidden j = 4m+quad, batch b = nn.
// => combine runs IN-REGISTER in the owning lane; c-state lives there too.
// Double-buffered panel makes ONE barrier per step legal:
//   iter s: read sB[s&1] (h1(s-1), x(s), h2(s-2)),
//           write sB[(s+1)&1] (h1(s), h2(s-1), x(s+1)).

__global__ __launch_bounds__(NT, 2) void lstm2_1bar(
    const float* __restrict__ x,
    const float* __restrict__ Wih0, const float* __restrict__ Whh0,
    const float* __restrict__ bih0, const float* __restrict__ bhh0,
    const float* __restrict__ Wih1, const float* __restrict__ Whh1,
    const float* __restrict__ bih1, const float* __restrict__ bhh1,
    const float* __restrict__ fcW,  const float* __restrict__ fcb,
    float* __restrict__ out)
{
    __shared__ _Float16 sB[2][PSZ];     // double-buffered panel, 14 KB
    __shared__ unsigned sXu[SEQ * NB];  // pre-split x (hi,lo), 16 KB
    __shared__ float    sH2f[H * NB];   // final h2

    const int t    = threadIdx.x;
    const int wave = t >> 6, lane = t & 63;
    const int quad = lane >> 4, nn = lane & 15;
    const int bbase = blockIdx.x * NB;

    // zero both panels (pads must stay 0 forever)
    for (int i = t; i < 2 * PSZ; i += NT) ((_Float16*)sB)[i] = (_Float16)0.f;

    // ---- pre-stage ALL x as f16 hi/lo pairs (coalesced global reads) ----
    for (int i = t; i < NB * SEQ; i += NT) {
        const int b = i >> 9, s = i & (SEQ - 1);
        float xv = x[(bbase + b) * SEQ + s];
        H2U p; p.h[0] = f16hi(xv); p.h[1] = f16lo(xv);
        sXu[s * NB + b] = p.u;
    }

    // ---- constant A-fragments (gate-permuted rows); wave w owns m=w, w+8 ----
    const bool m1v = (wave + 8 < MT);
    f16x8 a0[2][4];
    f16x8 a1[2][KQ];
    f32x4 b0v[2], b1v[2];
    #pragma unroll
    for (int i = 0; i < 2; ++i) {
        const int  m    = wave + 8 * i;
        const bool mv   = (i == 0) || m1v;
        const int  jr   = m * 4 + (nn >> 2);     // hidden unit of A phys row nn
        const int  gate = nn & 3;
        const bool rv   = mv && (jr < H);
        const int  lrow = gate * H + jr;         // logical W row
        #pragma unroll
        for (int q = 0; q < 4; ++q) {
            #pragma unroll
            for (int j = 0; j < 8; ++j) {
                const int k = q * 32 + quad * 8 + j;
                _Float16 v = (_Float16)0.f;
                if (rv) {
                    if      (k < 50)   v = f16hi(Whh0[lrow * H + k]);
                    else if (k < 100)  v = f16lo(Whh0[lrow * H + (k - 50)]);
                    else if (k == 100) v = f16hi(Wih0[lrow]);
                    else if (k == 101) v = f16lo(Wih0[lrow]);
                }
                a0[i][q][j] = v;
            }
        }
        #pragma unroll
        for (int q = 0; q < KQ; ++q) {
            #pragma unroll
            for (int j = 0; j < 8; ++j) {
                const int k = q * 32 + quad * 8 + j;
                _Float16 v = (_Float16)0.f;
                if (rv) {
                    if      (k < 50)              v = f16hi(Wih1[lrow * H + k]);
                    else if (k < 100)             v = f16lo(Wih1[lrow * H + (k - 50)]);
                    else if (k >= 112 && k < 162) v = f16hi(Whh1[lrow * H + (k - 112)]);
                    else if (k >= 162 && k < 212) v = f16lo(Whh1[lrow * H + (k - 162)]);
                }
                a1[i][q][j] = v;
            }
        }
        const int jq = m * 4 + quad;             // hidden unit of acc regs
        #pragma unroll
        for (int r = 0; r < 4; ++r) {
            const bool bv = mv && (jq < H);
            b0v[i][r] = bv ? (bih0[r * H + jq] + bhh0[r * H + jq]) : 0.f;
            b1v[i][r] = bv ? (bih1[r * H + jq] + bhh1[r * H + jq]) : 0.f;
        }
    }

    // per-lane cell states: (j = 4*wave+quad, b = nn) and (j+32, b = nn)
    const int j0 = wave * 4 + quad;          // < 32, always valid
    const int j1 = j0 + 32;                  // valid if < 50 (and m1v)
    const bool v0 = (nn < 8);
    const bool v1 = m1v && (nn < 8) && (j1 < H);
    float c0a = 0.f, c0b = 0.f, c1a = 0.f, c1b = 0.f;

    __syncthreads();
    if (t < NB) {                             // x(0) into panel 0
        H2U p; p.u = sXu[t];
        sB[0][baddr(100, t)] = p.h[0];
        sB[0][baddr(101, t)] = p.h[1];
    }
    __syncthreads();

    #pragma unroll 1
    for (int s = 0; s <= SEQ; ++s) {
        const _Float16* __restrict__ br = sB[s & 1];
        _Float16*       __restrict__ bw = sB[(s + 1) & 1];

        f16x8 bq[KQ];
        #pragma unroll
        for (int q = 0; q < KQ; ++q)
            bq[q] = *(const f16x8*)&br[(q * 64 + lane) * 8];

        // ---- L0 for step s: gates -> in-lane combine -> h1(s) into bw ----
        if (s < SEQ) {
            f32x4 acc0 = b0v[0];
            #pragma unroll
            for (int q = 0; q < 4; ++q)
                acc0 = __builtin_amdgcn_mfma_f32_16x16x32_f16(a0[0][q], bq[q], acc0, 0, 0, 0);
            if (v0) {
                c0a = sigm(acc0[1]) * c0a + sigm(acc0[0]) * tanh_fast(acc0[2]);
                float h = sigm(acc0[3]) * tanh_fast(c0a);
                bw[baddr(j0,      nn)] = f16hi(h);
                bw[baddr(j0 + 50, nn)] = f16lo(h);
            }
            if (m1v) {
                f32x4 acc1 = b0v[1];
                #pragma unroll
                for (int q = 0; q < 4; ++q)
                    acc1 = __builtin_amdgcn_mfma_f32_16x16x32_f16(a0[1][q], bq[q], acc1, 0, 0, 0);
                if (v1) {
                    c0b = sigm(acc1[1]) * c0b + sigm(acc1[0]) * tanh_fast(acc1[2]);
                    float h = sigm(acc1[3]) * tanh_fast(c0b);
                    bw[baddr(j1,      nn)] = f16hi(h);
                    bw[baddr(j1 + 50, nn)] = f16lo(h);
                }
            }
        }

        // ---- L1 for step s-1: gates -> in-lane combine -> h2(s-1) ----
        if (s >= 1) {
            f32x4 e0 = b1v[0], o0 = {0.f, 0.f, 0.f, 0.f};
            #pragma unroll
            for (int q = 0; q < KQ; q += 2)
                e0 = __builtin_amdgcn_mfma_f32_16x16x32_f16(a1[0][q], bq[q], e0, 0, 0, 0);
            #pragma unroll
            for (int q = 1; q < KQ; q += 2)
                o0 = __builtin_amdgcn_mfma_f32_16x16x32_f16(a1[0][q], bq[q], o0, 0, 0, 0);
            f32x4 g = e0 + o0;
            if (v0) {
                c1a = sigm(g[1]) * c1a + sigm(g[0]) * tanh_fast(g[2]);
                float h = sigm(g[3]) * tanh_fast(c1a);
                if (s == SEQ) sH2f[j0 * NB + nn] = h;
                else {
                    bw[baddr(j0 + 112, nn)] = f16hi(h);
                    bw[baddr(j0 + 162, nn)] = f16lo(h);
                }
            }
            if (m1v) {
                f32x4 e1 = b1v[1], o1 = {0.f, 0.f, 0.f, 0.f};
                #pragma unroll
                for (int q = 0; q < KQ; q += 2)
                    e1 = __builtin_amdgcn_mfma_f32_16x16x32_f16(a1[1][q], bq[q], e1, 0, 0, 0);
                #pragma unroll
                for (int q = 1; q < KQ; q += 2)
                    o1 = __builtin_amdgcn_mfma_f32_16x16x32_f16(a1[1][q], bq[q], o1, 0, 0, 0);
                f32x4 g1 = e1 + o1;
                if (v1) {
                    c1b = sigm(g1[1]) * c1b + sigm(g1[0]) * tanh_fast(g1[2]);
                    float h = sigm(g1[3]) * tanh_fast(c1b);
                    if (s == SEQ) sH2f[j1 * NB + nn] = h;
                    else {
                        bw[baddr(j1 + 112, nn)] = f16hi(h);
                        bw[baddr(j1 + 162, nn)] = f16lo(h);
                    }
                }
            }
        }

        // ---- x(s+1) into bw (wave 7 = the wave with no second tile) ----
        if (wave == 7 && lane < NB && s + 1 < SEQ) {
            H2U p; p.u = sXu[(s + 1) * NB + lane];
            bw[baddr(100, lane)] = p.h[0];
            bw[baddr(101, lane)] = p.h[1];
        }

        __syncthreads();   // the ONLY barrier per step
    }

    // ---- FC epilogue: out[b] = fcW . h2_last[b] + fcb ----
    if (t < NB) {
        float sum = fcb[0];
        #pragma unroll
        for (int jj = 0; jj < H; ++jj) sum += fcW[jj] * sH2f[jj * NB + t];
        out[bbase + t] = sum;
    }
}

extern "C" void kernel_launch(void* const* d_in, const int* in_sizes, int n_in,
                              void* d_out, int out_size, void* d_ws, size_t ws_size,
                              hipStream_t stream)
{
    const float* x    = (const float*)d_in[0];
    const float* Wih0 = (const float*)d_in[1];
    const float* Whh0 = (const float*)d_in[2];
    const float* bih0 = (const float*)d_in[3];
    const float* bhh0 = (const float*)d_in[4];
    const float* Wih1 = (const float*)d_in[5];
    const float* Whh1 = (const float*)d_in[6];
    const float* bih1 = (const float*)d_in[7];
    const float* bhh1 = (const float*)d_in[8];
    const float* fcW  = (const float*)d_in[9];
    const float* fcb  = (const float*)d_in[10];

    lstm2_1bar<<<BATCH / NB, NT, 0, stream>>>(
        x, Wih0, Whh0, bih0, bhh0, Wih1, Whh1, bih1, bhh1, fcW, fcb,
        (float*)d_out);
}

// Round 8
// 436.719 us; speedup vs baseline: 1.4880x; 1.4880x over previous
//
#include <hip/hip_runtime.h>

typedef _Float16 f16x8 __attribute__((ext_vector_type(8)));
typedef float    f32x4 __attribute__((ext_vector_type(4)));

constexpr int BATCH = 2048;
constexpr int SEQ   = 512;
constexpr int H     = 50;
constexpr int NB    = 8;     // batch per block -> 256 blocks = 1 per CU
constexpr int NT    = 1024;  // 16 waves, 4 per SIMD
constexpr int KQ    = 7;     // panel k-chunks of 32 (K=224)
constexpr int PSZ   = KQ * 64 * 8;   // panel halfs (3584)

__device__ __forceinline__ float fexp2(float x) { return __builtin_amdgcn_exp2f(x); }
__device__ __forceinline__ float frcp(float x)  { return __builtin_amdgcn_rcpf(x); }
__device__ __forceinline__ float sigm(float x) {
    return frcp(1.0f + fexp2(-1.4426950408889634f * x));
}
__device__ __forceinline__ float tanh_fast(float x) {
    float a = fexp2(-2.8853900817779268f * fabsf(x));
    return copysignf((1.0f - a) * frcp(1.0f + a), x);
}
__device__ __forceinline__ _Float16 f16hi(float w) { return (_Float16)w; }
__device__ __forceinline__ _Float16 f16lo(float w) {
    _Float16 h = (_Float16)w; return (_Float16)(w - (float)h);
}
// B-panel frag-linear address (halfs) for value (k, n), k<224, n<16
__device__ __forceinline__ int baddr(int k, int n) {
    return (((k >> 5) * 64) + (((k >> 3) & 3) * 16) + n) * 8 + (k & 7);
}
union H2U { unsigned u; _Float16 h[2]; };
union FI  { float f; int i; };

// Panel k-map (hi/lo INTERLEAVED so each h is one b32 write):
//   k in [0,100):   h1 unit j=k>>1, k&1 ? lo : hi
//   k 100,101:      x hi, lo
//   k [102,112):    zero pad
//   k [112,212):    h2 unit j=(k-112)>>1, k&1 ? lo : hi
//   k [212,224):    zero pad
// GATE PERMUTATION (as r6/r7): tile m phys row w <-> jj = 4m+(w>>2), gate w&3.
// After MFMA, lane (quad,nn) reg r = gate r of hidden jj = 4m+quad, batch nn.
// COMBINE SIMD-IFICATION: lanes nn<8 combine L0(batch nn); lanes nn>=8 combine
// L1(batch nn-8) using gates bpermuted from lane-8.  One code path, 64 lanes.
// Schedule (1 barrier/step): iter s reads sB[s&1] = {h1(s-1), x(s), h2(s-2)},
// writes sB[(s+1)&1] = {h1(s), x(s+1), h2(s-1)}.

__global__ __launch_bounds__(NT, 4) void lstm2_wide(
    const float* __restrict__ x,
    const float* __restrict__ Wih0, const float* __restrict__ Whh0,
    const float* __restrict__ bih0, const float* __restrict__ bhh0,
    const float* __restrict__ Wih1, const float* __restrict__ Whh1,
    const float* __restrict__ bih1, const float* __restrict__ bhh1,
    const float* __restrict__ fcW,  const float* __restrict__ fcb,
    float* __restrict__ out)
{
    __shared__ _Float16 sB[2][PSZ];     // double-buffered panel, 14 KB
    __shared__ unsigned sXu[SEQ * NB];  // pre-split x (hi,lo), 16 KB
    __shared__ float    sH2f[H * NB];   // final h2

    const int t    = threadIdx.x;
    const int wave = t >> 6, lane = t & 63;
    const int quad = lane >> 4, nn = lane & 15;
    const int bbase = blockIdx.x * NB;

    // zero both panels (pads must stay 0 forever)
    for (int i = t; i < 2 * PSZ; i += NT) ((_Float16*)sB)[i] = (_Float16)0.f;

    // ---- pre-stage ALL x as packed f16 hi/lo pairs (coalesced) ----
    for (int i = t; i < NB * SEQ; i += NT) {
        const int b = i >> 9, s = i & (SEQ - 1);
        float xv = x[(bbase + b) * SEQ + s];
        H2U p; p.h[0] = f16hi(xv); p.h[1] = f16lo(xv);
        sXu[s * NB + b] = p.u;
    }

    // ---- constant A-fragments; wave w owns tile m = w (13 active waves) ----
    const bool mmv = (wave < 13);
    f16x8 a0[4];       // L0: chunks 0..3 (K=128)
    f16x8 a1[KQ];      // L1: chunks 0..6 (K=224)
    f32x4 b0v = {0,0,0,0}, b1v = {0,0,0,0};
    if (mmv) {
        const int  m    = wave;
        const int  jr   = m * 4 + (nn >> 2);     // hidden unit of A phys row nn
        const int  gate = nn & 3;
        const bool rv   = (jr < H);
        const int  lrow = gate * H + jr;         // logical W row
        #pragma unroll
        for (int q = 0; q < 4; ++q) {
            #pragma unroll
            for (int j = 0; j < 8; ++j) {
                const int k = q * 32 + quad * 8 + j;
                _Float16 v = (_Float16)0.f;
                if (rv) {
                    if (k < 100) {
                        float w = Whh0[lrow * H + (k >> 1)];
                        v = (k & 1) ? f16lo(w) : f16hi(w);
                    } else if (k == 100) v = f16hi(Wih0[lrow]);
                    else if (k == 101)   v = f16lo(Wih0[lrow]);
                }
                a0[q][j] = v;
            }
        }
        #pragma unroll
        for (int q = 0; q < KQ; ++q) {
            #pragma unroll
            for (int j = 0; j < 8; ++j) {
                const int k = q * 32 + quad * 8 + j;
                _Float16 v = (_Float16)0.f;
                if (rv) {
                    if (k < 100) {
                        float w = Wih1[lrow * H + (k >> 1)];
                        v = (k & 1) ? f16lo(w) : f16hi(w);
                    } else if (k >= 112 && k < 212) {
                        float w = Whh1[lrow * H + ((k - 112) >> 1)];
                        v = (k & 1) ? f16lo(w) : f16hi(w);
                    }
                }
                a1[q][j] = v;
            }
        }
        const int jq = m * 4 + quad;
        #pragma unroll
        for (int r = 0; r < 4; ++r) {
            const bool bv = (jq < H);
            b0v[r] = bv ? (bih0[r * H + jq] + bhh0[r * H + jq]) : 0.f;
            b1v[r] = bv ? (bih1[r * H + jq] + bhh1[r * H + jq]) : 0.f;
        }
    }

    // per-lane combine identity
    const int  jj   = wave * 4 + quad;       // hidden unit (valid < 50)
    const bool hiH  = (nn >= 8);             // hi lanes combine L1
    const int  col  = nn & 7;                // batch
    const int  kb   = hiH ? (112 + 2 * jj) : (2 * jj);
    const int  wU   = baddr(kb, col) >> 1;   // u32 index of this lane's h slot
    const int  bpa  = ((lane - 8) & 63) << 2;// bpermute byte-index (src lane-8)
    const bool wrOK = mmv && (jj < H);
    float c = 0.f;                           // c0 (lo lanes) or c1 (hi lanes)

    __syncthreads();
    if (t < NB)                              // x(0) into panel 0
        ((unsigned*)sB[0])[baddr(100, t) >> 1] = sXu[t];
    __syncthreads();

    const _Float16* br = sB[0];
    _Float16*       bw = sB[1];

    #pragma unroll 1
    for (int s = 0; s <= SEQ; ++s) {
        if (mmv) {
            f16x8 bq[KQ];
            #pragma unroll
            for (int q = 0; q < KQ; ++q)
                bq[q] = *(const f16x8*)&br[(q * 64 + lane) * 8];

            // L0 gates (step s) and L1 gates (step s-1); both unconditional,
            // edge iterations are handled by the combine predicate.
            f32x4 g0 = b0v;
            #pragma unroll
            for (int q = 0; q < 4; ++q)
                g0 = __builtin_amdgcn_mfma_f32_16x16x32_f16(a0[q], bq[q], g0, 0, 0, 0);
            f32x4 g1 = b1v;
            #pragma unroll
            for (int q = 0; q < KQ; ++q)
                g1 = __builtin_amdgcn_mfma_f32_16x16x32_f16(a1[q], bq[q], g1, 0, 0, 0);

            // merge: lo lanes take g0; hi lanes take g1 from lane-8
            f32x4 g;
            #pragma unroll
            for (int r = 0; r < 4; ++r) {
                FI u; u.f = g1[r];
                FI v; v.i = __builtin_amdgcn_ds_bpermute(bpa, u.i);
                g[r] = hiH ? v.f : g0[r];
            }

            // combine (valid: lo lanes for s<SEQ, hi lanes for s>=1)
            const bool doC = hiH ? (s != 0) : (s != SEQ);
            if (doC) {
                c = sigm(g[1]) * c + sigm(g[0]) * tanh_fast(g[2]);
                float h = sigm(g[3]) * tanh_fast(c);
                if (wrOK) {
                    if (hiH && s == SEQ) {
                        sH2f[jj * NB + col] = h;     // h2(511) for the FC
                    } else {
                        _Float16 hh = f16hi(h);
                        H2U p; p.h[0] = hh; p.h[1] = (_Float16)(h - (float)hh);
                        ((unsigned*)bw)[wU] = p.u;   // one packed b32 write
                    }
                }
            }
        } else if (wave == 15 && lane < NB && s + 1 < SEQ) {
            // x(s+1) into the write panel
            ((unsigned*)bw)[baddr(100, lane) >> 1] = sXu[(s + 1) * NB + lane];
        }

        __syncthreads();   // the ONLY barrier per step
        const _Float16* tmp = br; br = bw; bw = (_Float16*)tmp;
    }

    // ---- FC epilogue: out[b] = fcW . h2_last[b] + fcb ----
    if (t < NB) {
        float sum = fcb[0];
        #pragma unroll
        for (int jx = 0; jx < H; ++jx) sum += fcW[jx] * sH2f[jx * NB + t];
        out[bbase + t] = sum;
    }
}

extern "C" void kernel_launch(void* const* d_in, const int* in_sizes, int n_in,
                              void* d_out, int out_size, void* d_ws, size_t ws_size,
                              hipStream_t stream)
{
    const float* x    = (const float*)d_in[0];
    const float* Wih0 = (const float*)d_in[1];
    const float* Whh0 = (const float*)d_in[2];
    const float* bih0 = (const float*)d_in[3];
    const float* bhh0 = (const float*)d_in[4];
    const float* Wih1 = (const float*)d_in[5];
    const float* Whh1 = (const float*)d_in[6];
    const float* bih1 = (const float*)d_in[7];
    const float* bhh1 = (const float*)d_in[8];
    const float* fcW  = (const float*)d_in[9];
    const float* fcb  = (const float*)d_in[10];

    lstm2_wide<<<BATCH / NB, NT, 0, stream>>>(
        x, Wih0, Whh0, bih0, bhh0, Wih1, Whh1, bih1, bhh1, fcW, fcb,
        (float*)d_out);
}

// Round 9
// 408.259 us; speedup vs baseline: 1.5917x; 1.0697x over previous
//
#include <hip/hip_runtime.h>

typedef _Float16 f16x8 __attribute__((ext_vector_type(8)));
typedef float    f32x4 __attribute__((ext_vector_type(4)));

constexpr int BATCH = 2048;
constexpr int SEQ   = 512;
constexpr int H     = 50;
constexpr int NB    = 8;     // batch per block -> 256 blocks = 1 per CU
constexpr int NT    = 1024;  // 16 waves, 4 per SIMD
constexpr int KQ    = 7;     // panel k-chunks of 32 (K=224)
constexpr int PSZ   = KQ * 64 * 8;   // panel halfs (3584)

__device__ __forceinline__ float fexp2(float x) { return __builtin_amdgcn_exp2f(x); }
__device__ __forceinline__ float frcp(float x)  { return __builtin_amdgcn_rcpf(x); }
__device__ __forceinline__ _Float16 f16hi(float w) { return (_Float16)w; }
__device__ __forceinline__ _Float16 f16lo(float w) {
    _Float16 h = (_Float16)w; return (_Float16)(w - (float)h);
}
// B-panel frag-linear address (halfs) for value (k, n), k<224, n<16
__device__ __forceinline__ int baddr(int k, int n) {
    return (((k >> 5) * 64) + (((k >> 3) & 3) * 16) + n) * 8 + (k & 7);
}
union H2U { unsigned u; _Float16 h[2]; };

constexpr float K1 = 1.4426950408889634f;   // log2(e)
constexpr float K2 = 2.8853900817779268f;   // 2*log2(e)

// Panel k-map (hi/lo interleaved): k in [0,100): h1 unit j=k>>1 (odd=lo);
// k 100,101: x hi,lo; [102,112): pad; [112,212): h2 unit j=(k-112)>>1;
// [212,224): pad.  COLUMNS: n in 0..7 = batch n, n in 8..15 = DUPLICATE of
// batch n-8.  So lane nn>=8's own g1 is L1's preact for batch nn-8 -> the
// L0/L1 merge is a cndmask, no bpermute.  Each combine writes its h to both
// column copies (2x b32, 2-way bank pattern = conflict-free).
// GATE PERMUTATION (as r8): tile m phys row w <-> jj = 4m+(w>>2), gate w&3.
// Schedule (1 barrier/step): iter s reads sB[s&1] = {h1(s-1), x(s), h2(s-2)},
// writes sB[(s+1)&1] = {h1(s), x(s+1), h2(s-1)}.  Unroll-2 makes the panel
// pointers compile-time; edge iterations (s=0,511,512) are peeled.

__global__ __launch_bounds__(NT, 4) void lstm2_dup(
    const float* __restrict__ x,
    const float* __restrict__ Wih0, const float* __restrict__ Whh0,
    const float* __restrict__ bih0, const float* __restrict__ bhh0,
    const float* __restrict__ Wih1, const float* __restrict__ Whh1,
    const float* __restrict__ bih1, const float* __restrict__ bhh1,
    const float* __restrict__ fcW,  const float* __restrict__ fcb,
    float* __restrict__ out)
{
    __shared__ _Float16 sB[2][PSZ];     // double-buffered panel, 14 KB
    __shared__ unsigned sXu[SEQ * NB];  // pre-split x (hi,lo), 16 KB
    __shared__ float    sH2f[H * NB];   // final h2

    const int t    = threadIdx.x;
    const int wave = t >> 6, lane = t & 63;
    const int quad = lane >> 4, nn = lane & 15;
    const int bbase = blockIdx.x * NB;

    // zero both panels (pads must stay 0 forever)
    for (int i = t; i < 2 * PSZ; i += NT) ((_Float16*)sB)[i] = (_Float16)0.f;

    // ---- pre-stage ALL x as packed f16 hi/lo pairs (coalesced) ----
    for (int i = t; i < NB * SEQ; i += NT) {
        const int b = i >> 9, s = i & (SEQ - 1);
        float xv = x[(bbase + b) * SEQ + s];
        H2U p; p.h[0] = f16hi(xv); p.h[1] = f16lo(xv);
        sXu[s * NB + b] = p.u;
    }

    // ---- constant A-fragments; wave w owns tile m = w (13 active waves) ----
    const bool mmv = (wave < 13);
    f16x8 a0[4];       // L0: chunks 0..3 (K=128)
    f16x8 a1[KQ];      // L1: chunks 0..6 (K=224)
    f32x4 b0v = {0,0,0,0}, b1v = {0,0,0,0};
    if (mmv) {
        const int  m    = wave;
        const int  jr   = m * 4 + (nn >> 2);     // hidden unit of A phys row nn
        const int  gate = nn & 3;
        const bool rv   = (jr < H);
        const int  lrow = gate * H + jr;         // logical W row
        #pragma unroll
        for (int q = 0; q < 4; ++q) {
            #pragma unroll
            for (int j = 0; j < 8; ++j) {
                const int k = q * 32 + quad * 8 + j;
                _Float16 v = (_Float16)0.f;
                if (rv) {
                    if (k < 100) {
                        float w = Whh0[lrow * H + (k >> 1)];
                        v = (k & 1) ? f16lo(w) : f16hi(w);
                    } else if (k == 100) v = f16hi(Wih0[lrow]);
                    else if (k == 101)   v = f16lo(Wih0[lrow]);
                }
                a0[q][j] = v;
            }
        }
        #pragma unroll
        for (int q = 0; q < KQ; ++q) {
            #pragma unroll
            for (int j = 0; j < 8; ++j) {
                const int k = q * 32 + quad * 8 + j;
                _Float16 v = (_Float16)0.f;
                if (rv) {
                    if (k < 100) {
                        float w = Wih1[lrow * H + (k >> 1)];
                        v = (k & 1) ? f16lo(w) : f16hi(w);
                    } else if (k >= 112 && k < 212) {
                        float w = Whh1[lrow * H + ((k - 112) >> 1)];
                        v = (k & 1) ? f16lo(w) : f16hi(w);
                    }
                }
                a1[q][j] = v;
            }
        }
        const int jq = m * 4 + quad;
        #pragma unroll
        for (int r = 0; r < 4; ++r) {
            const bool bv = (jq < H);
            b0v[r] = bv ? (bih0[r * H + jq] + bhh0[r * H + jq]) : 0.f;
            b1v[r] = bv ? (bih1[r * H + jq] + bhh1[r * H + jq]) : 0.f;
        }
    }

    // per-lane combine identity
    const int  jj   = wave * 4 + quad;        // hidden unit (valid < 50)
    const bool hiH  = (nn >= 8);              // hi lanes combine L1
    const int  col  = nn & 7;                 // batch
    const int  kb   = hiH ? (112 + 2 * jj) : (2 * jj);
    const int  wU0  = baddr(kb, col)     >> 1;  // u32 slot, column copy 0
    const int  wU1  = baddr(kb, col + 8) >> 1;  // u32 slot, column copy 1
    const bool wrOK = mmv && (jj < H);
    float c = 0.f;                            // c0 (lo lanes) or c1 (hi lanes)

    // x-staging lane constants (wave 15, lanes 0..15 cover both copies)
    const int xcol = lane & 7;
    const int xad  = baddr(100, (lane & 7) + 8 * ((lane >> 3) & 1)) >> 1;

    __syncthreads();
    if (t < 16)                               // x(0), both column copies
        ((unsigned*)sB[0])[baddr(100, (t & 7) + 8 * (t >> 3)) >> 1] = sXu[t & 7];
    __syncthreads();

    auto body = [&](int s, const _Float16* __restrict__ br,
                    _Float16* __restrict__ bw,
                    bool doL0, bool doL1, bool doX, bool last) {
        if (mmv) {
            f16x8 bq[KQ];
            #pragma unroll
            for (int q = 0; q < KQ; ++q)
                bq[q] = *(const f16x8*)&br[(q * 64 + lane) * 8];

            f32x4 g0 = b0v;
            #pragma unroll
            for (int q = 0; q < 4; ++q)
                g0 = __builtin_amdgcn_mfma_f32_16x16x32_f16(a0[q], bq[q], g0, 0, 0, 0);
            f32x4 g1 = b1v;
            #pragma unroll
            for (int q = 0; q < KQ; ++q)
                g1 = __builtin_amdgcn_mfma_f32_16x16x32_f16(a1[q], bq[q], g1, 0, 0, 0);

            f32x4 g;
            #pragma unroll
            for (int r = 0; r < 4; ++r) g[r] = hiH ? g1[r] : g0[r];

            const bool act = hiH ? doL1 : doL0;
            if (act) {
                float Ei = fexp2(-K1 * g[0]);
                float Ef = fexp2(-K1 * g[1]);
                float Eg = fexp2(-K2 * fabsf(g[2]));
                float Eo = fexp2(-K1 * g[3]);
                float it = copysignf((1.f - Eg) * frcp((1.f + Ei) * (1.f + Eg)), g[2]);
                c = frcp(1.f + Ef) * c + it;
                float Ec = fexp2(-K2 * fabsf(c));
                float h  = copysignf((1.f - Ec) * frcp((1.f + Eo) * (1.f + Ec)), c);
                if (wrOK) {
                    if (last && hiH) {
                        sH2f[jj * NB + col] = h;        // h2(511) for the FC
                    } else {
                        _Float16 hh = f16hi(h);
                        H2U p; p.h[0] = hh; p.h[1] = (_Float16)(h - (float)hh);
                        ((unsigned*)bw)[wU0] = p.u;     // column copy 0
                        ((unsigned*)bw)[wU1] = p.u;     // column copy 1
                    }
                }
            }
        } else if (doX && wave == 15 && lane < 16) {
            ((unsigned*)bw)[xad] = sXu[(s + 1) * NB + xcol];
        }
        __syncthreads();   // the ONLY barrier per step
    };

    body(0, sB[0], sB[1], true, false, true, false);
    #pragma unroll 1
    for (int i = 0; i < 255; ++i) {
        body(2 * i + 1, sB[1], sB[0], true, true, true, false);
        body(2 * i + 2, sB[0], sB[1], true, true, true, false);
    }
    body(511, sB[1], sB[0], true, true, false, false);
    body(512, sB[0], sB[1], false, true, false, true);

    // ---- FC epilogue: out[b] = fcW . h2_last[b] + fcb ----
    if (t < NB) {
        float sum = fcb[0];
        #pragma unroll
        for (int jx = 0; jx < H; ++jx) sum += fcW[jx] * sH2f[jx * NB + t];
        out[bbase + t] = sum;
    }
}

extern "C" void kernel_launch(void* const* d_in, const int* in_sizes, int n_in,
                              void* d_out, int out_size, void* d_ws, size_t ws_size,
                              hipStream_t stream)
{
    const float* x    = (const float*)d_in[0];
    const float* Wih0 = (const float*)d_in[1];
    const float* Whh0 = (const float*)d_in[2];
    const float* bih0 = (const float*)d_in[3];
    const float* bhh0 = (const float*)d_in[4];
    const float* Wih1 = (const float*)d_in[5];
    const float* Whh1 = (const float*)d_in[6];
    const float* bih1 = (const float*)d_in[7];
    const float* bhh1 = (const float*)d_in[8];
    const float* fcW  = (const float*)d_in[9];
    const float* fcb  = (const float*)d_in[10];

    lstm2_dup<<<BATCH / NB, NT, 0, stream>>>(
        x, Wih0, Whh0, bih0, bhh0, Wih1, Whh1, bih1, bhh1, fcW, fcb,
        (float*)d_out);
}